// Round 17
// baseline (174.499 us; speedup 1.0000x reference)
//
#include <hip/hip_runtime.h>
#include <hip/hip_bf16.h>

#define N_NODES 20000
#define N_EDGES 320000
#define IN_DIM  1024
#define H_HEADS 8
#define C_CH    64
#define HC      512
#define LEAKY   0.2f
#define LN_EPS  1e-5f

// Extended columns: 0..511 = W_src, 512..519 = att_src fold, 520..527 =
// att_dst fold, 528..575 = zero pad.
#define BCOLS 576
#define NCT   36            // 576/16 column tiles
#define NKT   32            // 1024/32 k tiles
#define NRT   1250          // 20000/16 row tiles  (exact)

// Fragment-native tile: 16 (rows|cols) x 32 k, element order = MFMA lane
// order: [kgroup 0..3][lane-row 0..15][8 bf16] -> a wave's A/B fragment is
// ONE fully-coalesced 1KB load at tile_base + lane*16B.  (R7's barrier-free
// GEMM failed on 64-transactions-per-load; this layout makes it 1.)

typedef short bf16x8 __attribute__((ext_vector_type(8)));
typedef float f32x4  __attribute__((ext_vector_type(4)));

__device__ __forceinline__ unsigned short f2bf(float f) {
    union { float f; unsigned int u; } c; c.f = f;
    unsigned int u = c.u;
    unsigned int r = (u + 0x7fffu + ((u >> 16) & 1u)) >> 16;   // RNE
    return (unsigned short)r;
}
__device__ __forceinline__ float bf2f(unsigned int h) {
    union { unsigned int u; float f; } c; c.u = h << 16; return c.f;
}
// HW packed f32->bf16 (RNE), 1 instr per 2 elements
__device__ __forceinline__ unsigned int cvtpk(float lo, float hi) {
    unsigned int r;
    asm("v_cvt_pk_bf16_f32 %0, %1, %2" : "=v"(r) : "v"(lo), "v"(hi));
    return r;
}

// ---------------------------------------------------------------------------
// Fused pre-pass, three independent block ranges:
//   [0,1250)      deg histogram
//   [1250,2500)   x fp32 -> xbt bf16 fragment-tiled (block = 1 row-tile rt)
//   [2500,2532)   weight fold + retile -> wbtt (block = 1 k-tile kt)
#define DEG_BLOCKS 1250
#define CONV_BLOCKS NRT
#define PREP_BLOCKS NKT

__global__ __launch_bounds__(256) void fused_pre(
        const float* __restrict__ x,
        const int* __restrict__ ei,
        const float* __restrict__ Wsrc,
        const float* __restrict__ Wdst,
        const float* __restrict__ att_src,
        const float* __restrict__ att_dst,
        short* __restrict__ xbt,
        short* __restrict__ wbtt,
        int* __restrict__ deg) {
    __shared__ short sw[32 * 512];          // 32 KB: bf16 Wsrc rows k0..k0+31
    __shared__ float f1[32][8], f2[32][8];  // fold values (fp32)
    int t   = threadIdx.x;
    int bid = blockIdx.x;

    if (bid < DEG_BLOCKS) {                 // ---- deg histogram
        int e = bid * 256 + t;              // 1250*256 == N_EDGES
        atomicAdd(&deg[ei[N_EDGES + e]], 1);
        return;
    }

    if (bid < DEG_BLOCKS + CONV_BLOCKS) {   // ---- x -> xbt retile
        int rt   = bid - DEG_BLOCKS;        // 0..1249
        int lane = t & 63, w = t >> 6;
        int lr = lane & 15, lg = lane >> 4;
        const float* xr = x + (size_t)(rt * 16 + lr) * IN_DIM;
        #pragma unroll
        for (int i = 0; i < 8; ++i) {
            int kt = w + i * 4;             // covers 0..31 across 4 waves
            float4 f = *(const float4*)(xr + kt * 32 + lg * 8);
            float4 g = *(const float4*)(xr + kt * 32 + lg * 8 + 4);
            uint4 r;
            r.x = cvtpk(f.x, f.y);  r.y = cvtpk(f.z, f.w);
            r.z = cvtpk(g.x, g.y);  r.w = cvtpk(g.z, g.w);
            *(uint4*)(xbt + (((size_t)rt * 32 + kt) << 9) + lane * 8) = r;
        }
        return;
    }

    // ---- weight fold + retile (one k-tile of 32 k's per block)
    int kt = bid - (DEG_BLOCKS + CONV_BLOCKS);   // 0..31
    int k0 = kt * 32;
    // stage bf16 Wsrc rows into LDS (coalesced float4 reads)
    for (int i = t; i < 32 * 128; i += 256) {
        int kk = i >> 7, g4 = i & 127;
        float4 v = *(const float4*)(Wsrc + (size_t)(k0 + kk) * HC + g4 * 4);
        uint2 p;
        p.x = cvtpk(v.x, v.y);  p.y = cvtpk(v.z, v.w);
        *(uint2*)(&sw[kk * 512 + g4 * 4]) = p;
    }
    // folds from global fp32 (matches previous numerics)
    {
        int kk = t >> 3, h = t & 7;
        const float* wsr = Wsrc + (size_t)(k0 + kk) * HC + h * 64;
        const float* wdr = Wdst + (size_t)(k0 + kk) * HC + h * 64;
        const float* a1  = att_src + h * 64;
        const float* a2  = att_dst + h * 64;
        float s1 = 0.f, s2 = 0.f;
        #pragma unroll 8
        for (int c = 0; c < 64; ++c) {
            s1 += wsr[c] * a1[c];
            s2 += wdr[c] * a2[c];
        }
        f1[kk][h] = s1;  f2[kk][h] = s2;
    }
    __syncthreads();
    // write 36 fragment tiles
    for (int idx = t; idx < NCT * 64; idx += 256) {
        int ct = idx >> 6, sl = idx & 63;
        int lr = sl & 15, lg = sl >> 4;
        int col = ct * 16 + lr;
        union { short v[8]; uint4 u; } pk;
        #pragma unroll
        for (int j = 0; j < 8; ++j) {
            int kk = lg * 8 + j;
            short val;
            if (col < 512)      val = sw[kk * 512 + col];
            else if (col < 520) val = (short)f2bf(f1[kk][col - 512]);
            else if (col < 528) val = (short)f2bf(f2[kk][col - 520]);
            else                val = 0;
            pk.v[j] = val;
        }
        *(uint4*)(wbtt + (((size_t)ct * 32 + kt) << 9) + sl * 8) = pk.u;
    }
}

// ---------------------------------------------------------------------------
// BARRIER-FREE MFMA GEMM: no LDS, no __syncthreads, no waitcnt asm.
// Each wave owns a 32x48 output tile and streams 32 k-tiles; every A/B
// fragment is one coalesced 1KB global load (fragment-native layout).
// Latency is hidden by ILP + free wave slip (no lockstep).
// Block = 4 waves (2 row groups x 2 col groups) -> 64x96 tile.
// Last row-block overlaps (row0=19936) so all rows < N_NODES (idempotent
// double-writes).  Block NWG = deg->off/cursor scan (needs deg, launch A).
#define NCOLT 6                             // 576 / 96
#define NROWT 313
#define NWG (NROWT * NCOLT)                 // 1878

__global__ __launch_bounds__(256) void gemm_scan(
        const short* __restrict__ xbt,
        const short* __restrict__ wbtt,
        short* __restrict__ xsb,
        float* __restrict__ a_srcv,
        float* __restrict__ a_dstv,
        const int* __restrict__ deg,
        int* __restrict__ off,
        int* __restrict__ cursor) {
    int t = threadIdx.x;

    if (blockIdx.x == NWG) {                // ---- scan tail block
        __shared__ int wtot[2];
        int lane = t & 63, wv = t >> 6;
        const int4* deg4 = (const int4*)deg;
        int s = 0;
        if (t < 125) {                      // 125*160 == N_NODES
            #pragma unroll
            for (int j = 0; j < 40; ++j) {
                int4 u = deg4[t * 40 + j];
                s += u.x + u.y + u.z + u.w;
            }
        }
        int v = s;
        #pragma unroll
        for (int o = 1; o < 64; o <<= 1) {
            int u = __shfl_up(v, o);
            if (lane >= o) v += u;
        }
        if (lane == 63 && wv < 2) wtot[wv] = v;
        __syncthreads();
        int add = (wv == 1) ? wtot[0] : 0;
        int run = add + v - s;
        if (t < 125) {
            int4* off4 = (int4*)off;
            int4* cur4 = (int4*)cursor;
            #pragma unroll
            for (int j = 0; j < 40; ++j) {
                int4 u = deg4[t * 40 + j];
                int4 o_;
                o_.x = run;
                o_.y = o_.x + u.x;
                o_.z = o_.y + u.y;
                o_.w = o_.z + u.z;
                off4[t * 40 + j] = o_;
                cur4[t * 40 + j] = o_;
                run = o_.w + u.w;
            }
            if (t == 124) off[N_NODES] = run;
        }
        return;
    }

    // bijective XCD swizzle (m204)
    int orig = blockIdx.x;
    const int q = NWG >> 3, r = NWG & 7;
    int xcd  = orig & 7;
    int wgid = (xcd < r ? xcd * (q + 1) : r * (q + 1) + (xcd - r) * q) + (orig >> 3);
    int colblk = wgid % NCOLT;              // col tiles fastest -> A L2-local
    int rowblk = wgid / NCOLT;
    int row0 = (rowblk < NROWT - 1) ? rowblk * 64 : (N_NODES - 64);  // 19936

    int lane = t & 63;
    int w    = t >> 6;
    int lr   = lane & 15;
    int lg   = lane >> 4;
    int rtw  = (row0 >> 4) + (w >> 1) * 2;  // wave's first row tile (owns 2)
    int ctw  = colblk * 6 + (w & 1) * 3;    // wave's first col tile (owns 3)

    const short* pa0 = xbt  + (((size_t)(rtw + 0) * 32) << 9) + lane * 8;
    const short* pa1 = xbt  + (((size_t)(rtw + 1) * 32) << 9) + lane * 8;
    const short* pb0 = wbtt + (((size_t)(ctw + 0) * 32) << 9) + lane * 8;
    const short* pb1 = wbtt + (((size_t)(ctw + 1) * 32) << 9) + lane * 8;
    const short* pb2 = wbtt + (((size_t)(ctw + 2) * 32) << 9) + lane * 8;

    f32x4 acc[2][3] = {};

    #pragma unroll 4
    for (int kt = 0; kt < NKT; ++kt) {
        bf16x8 a0 = *(const bf16x8*)(pa0 + kt * 512);
        bf16x8 a1 = *(const bf16x8*)(pa1 + kt * 512);
        bf16x8 b0 = *(const bf16x8*)(pb0 + kt * 512);
        bf16x8 b1 = *(const bf16x8*)(pb1 + kt * 512);
        bf16x8 b2 = *(const bf16x8*)(pb2 + kt * 512);
        acc[0][0] = __builtin_amdgcn_mfma_f32_16x16x32_bf16(a0, b0, acc[0][0], 0, 0, 0);
        acc[0][1] = __builtin_amdgcn_mfma_f32_16x16x32_bf16(a0, b1, acc[0][1], 0, 0, 0);
        acc[0][2] = __builtin_amdgcn_mfma_f32_16x16x32_bf16(a0, b2, acc[0][2], 0, 0, 0);
        acc[1][0] = __builtin_amdgcn_mfma_f32_16x16x32_bf16(a1, b0, acc[1][0], 0, 0, 0);
        acc[1][1] = __builtin_amdgcn_mfma_f32_16x16x32_bf16(a1, b1, acc[1][1], 0, 0, 0);
        acc[1][2] = __builtin_amdgcn_mfma_f32_16x16x32_bf16(a1, b2, acc[1][2], 0, 0, 0);
    }

    // epilogue: C/D layout col=lane&15, row=(lane>>4)*4+reg; rows all valid.
    #pragma unroll
    for (int mi = 0; mi < 2; ++mi) {
        #pragma unroll
        for (int rr = 0; rr < 4; ++rr) {
            int row = (rtw + mi) * 16 + lg * 4 + rr;
            #pragma unroll
            for (int ni = 0; ni < 3; ++ni) {
                int col = (ctw + ni) * 16 + lr;
                float v = acc[mi][ni][rr];
                if (col < 512)      xsb[(size_t)row * HC + col] = (short)f2bf(v);
                else if (col < 520) a_srcv[(size_t)row * 8 + (col - 512)] = v;
                else if (col < 528) a_dstv[(size_t)row * 8 + (col - 520)] = v;
            }
        }
    }
}

// ---------------------------------------------------------------------------
// bare CSR scatter (needs cursor from scan -> own launch)
__global__ __launch_bounds__(256) void edge_scatter(
        const int* __restrict__ ei,
        int* __restrict__ cursor,
        int* __restrict__ csr_src) {
    int e = blockIdx.x * 256 + threadIdx.x;     // 1250*256 == N_EDGES
    int d = ei[N_EDGES + e];
    int idx = atomicAdd(&cursor[d], 1);
    csr_src[idx] = ei[e];
}

// ---------------------------------------------------------------------------
// ONE WAVE per destination node (4 independent waves/block, no barriers).
__global__ __launch_bounds__(256) void aggregate_ln(
        const int* __restrict__ off,
        const int* __restrict__ csr_src,
        const float* __restrict__ a_srcv,
        const float* __restrict__ a_dstv,
        const short* __restrict__ xsb,
        const float* __restrict__ bias,
        const float* __restrict__ gamma,
        const float* __restrict__ beta,
        const float* __restrict__ prelu_a,
        float* __restrict__ out) {
    int lane = threadIdx.x & 63;
    int n    = blockIdx.x * 4 + (threadIdx.x >> 6);   // 5000 x 4 waves = 20000
    int ch0  = lane * 8;
    int h    = lane >> 3;

    int start = off[n], end = off[n + 1];
    float ad  = a_dstv[(size_t)n * 8 + h];

    float acc[8] = {};
    float wsum = 0.f;

    int i = start;
    for (; i + 1 < end; i += 2) {
        int s0 = __builtin_amdgcn_readfirstlane(csr_src[i]);
        int s1 = __builtin_amdgcn_readfirstlane(csr_src[i + 1]);
        float sc0 = a_srcv[(size_t)s0 * 8 + h] + ad;
        float sc1 = a_srcv[(size_t)s1 * 8 + h] + ad;
        uint4 u0 = *(const uint4*)(xsb + (size_t)s0 * HC + ch0);
        uint4 u1 = *(const uint4*)(xsb + (size_t)s1 * HC + ch0);
        sc0 = (sc0 >= 0.f) ? sc0 : LEAKY * sc0;
        sc1 = (sc1 >= 0.f) ? sc1 : LEAKY * sc1;
        float w0 = __expf(sc0);
        float w1 = __expf(sc1);
        acc[0] = fmaf(w0, bf2f(u0.x & 0xffffu), acc[0]);
        acc[1] = fmaf(w0, bf2f(u0.x >> 16),     acc[1]);
        acc[2] = fmaf(w0, bf2f(u0.y & 0xffffu), acc[2]);
        acc[3] = fmaf(w0, bf2f(u0.y >> 16),     acc[3]);
        acc[4] = fmaf(w0, bf2f(u0.z & 0xffffu), acc[4]);
        acc[5] = fmaf(w0, bf2f(u0.z >> 16),     acc[5]);
        acc[6] = fmaf(w0, bf2f(u0.w & 0xffffu), acc[6]);
        acc[7] = fmaf(w0, bf2f(u0.w >> 16),     acc[7]);
        acc[0] = fmaf(w1, bf2f(u1.x & 0xffffu), acc[0]);
        acc[1] = fmaf(w1, bf2f(u1.x >> 16),     acc[1]);
        acc[2] = fmaf(w1, bf2f(u1.y & 0xffffu), acc[2]);
        acc[3] = fmaf(w1, bf2f(u1.y >> 16),     acc[3]);
        acc[4] = fmaf(w1, bf2f(u1.z & 0xffffu), acc[4]);
        acc[5] = fmaf(w1, bf2f(u1.z >> 16),     acc[5]);
        acc[6] = fmaf(w1, bf2f(u1.w & 0xffffu), acc[6]);
        acc[7] = fmaf(w1, bf2f(u1.w >> 16),     acc[7]);
        wsum += w0 + w1;
    }
    if (i < end) {
        int s0 = __builtin_amdgcn_readfirstlane(csr_src[i]);
        float sc0 = a_srcv[(size_t)s0 * 8 + h] + ad;
        uint4 u0 = *(const uint4*)(xsb + (size_t)s0 * HC + ch0);
        sc0 = (sc0 >= 0.f) ? sc0 : LEAKY * sc0;
        float w0 = __expf(sc0);
        acc[0] = fmaf(w0, bf2f(u0.x & 0xffffu), acc[0]);
        acc[1] = fmaf(w0, bf2f(u0.x >> 16),     acc[1]);
        acc[2] = fmaf(w0, bf2f(u0.y & 0xffffu), acc[2]);
        acc[3] = fmaf(w0, bf2f(u0.y >> 16),     acc[3]);
        acc[4] = fmaf(w0, bf2f(u0.z & 0xffffu), acc[4]);
        acc[5] = fmaf(w0, bf2f(u0.z >> 16),     acc[5]);
        acc[6] = fmaf(w0, bf2f(u0.w & 0xffffu), acc[6]);
        acc[7] = fmaf(w0, bf2f(u0.w >> 16),     acc[7]);
        wsum += w0;
    }

    float inv = 1.f / (wsum + 1e-16f);
    float4 b0 = *(const float4*)(bias + ch0);
    float4 b1 = *(const float4*)(bias + ch0 + 4);
    float v8[8];
    float psum = 0.f, psq = 0.f;
    const float bb[8] = {b0.x, b0.y, b0.z, b0.w, b1.x, b1.y, b1.z, b1.w};
    #pragma unroll
    for (int j = 0; j < 8; ++j) {
        v8[j] = acc[j] * inv + bb[j];
        psum += v8[j];
        psq  += v8[j] * v8[j];
    }
    #pragma unroll
    for (int o = 32; o > 0; o >>= 1) {
        psum += __shfl_xor(psum, o);
        psq  += __shfl_xor(psq, o);
    }
    float mu   = psum * (1.f / (float)HC);
    float var  = psq * (1.f / (float)HC) - mu * mu;
    float rstd = rsqrtf(var + LN_EPS);

    float4 g0 = *(const float4*)(gamma + ch0);
    float4 g1 = *(const float4*)(gamma + ch0 + 4);
    float4 e0 = *(const float4*)(beta + ch0);
    float4 e1 = *(const float4*)(beta + ch0 + 4);
    float4 p0 = *(const float4*)(prelu_a + ch0);
    float4 p1 = *(const float4*)(prelu_a + ch0 + 4);
    const float gg[8] = {g0.x, g0.y, g0.z, g0.w, g1.x, g1.y, g1.z, g1.w};
    const float ee[8] = {e0.x, e0.y, e0.z, e0.w, e1.x, e1.y, e1.z, e1.w};
    const float pp[8] = {p0.x, p0.y, p0.z, p0.w, p1.x, p1.y, p1.z, p1.w};
    float y[8];
    #pragma unroll
    for (int j = 0; j < 8; ++j) {
        float v = (v8[j] - mu) * rstd * gg[j] + ee[j];
        y[j] = (v >= 0.f) ? v : pp[j] * v;
    }
    float4* o4 = (float4*)(out + (size_t)n * HC + ch0);
    o4[0] = make_float4(y[0], y[1], y[2], y[3]);
    o4[1] = make_float4(y[4], y[5], y[6], y[7]);
}

// ---------------------------------------------------------------------------
extern "C" void kernel_launch(void* const* d_in, const int* in_sizes, int n_in,
                              void* d_out, int out_size, void* d_ws, size_t ws_size,
                              hipStream_t stream) {
    const float* x        = (const float*)d_in[0];
    const int*   ei       = (const int*)d_in[2];
    const float* Wsrc     = (const float*)d_in[4];
    const float* Wdst     = (const float*)d_in[5];
    const float* att_src  = (const float*)d_in[6];
    const float* att_dst  = (const float*)d_in[7];
    const float* bias     = (const float*)d_in[8];
    const float* gamma    = (const float*)d_in[9];
    const float* beta     = (const float*)d_in[10];
    const float* prelu_a  = (const float*)d_in[11];
    float* out            = (float*)d_out;

    char*  ws = (char*)d_ws;
    size_t o  = 0;
    auto alloc = [&](size_t bytes) -> void* {
        void* p = ws + o;
        o += (bytes + 255) & ~(size_t)255;
        return p;
    };
    short* wbtt    = (short*)alloc(sizeof(short) * NCT * NKT * 512);       // 1.18 MB
    short* xsb     = (short*)alloc(sizeof(short) * (size_t)N_NODES * HC);  // 20.5 MB
    float* a_srcv  = (float*)alloc(sizeof(float) * N_NODES * 8);
    float* a_dstv  = (float*)alloc(sizeof(float) * N_NODES * 8);
    int*   deg     = (int*)alloc(sizeof(int) * N_NODES);
    int*   off     = (int*)alloc(sizeof(int) * (N_NODES + 1));
    int*   cursor  = (int*)alloc(sizeof(int) * N_NODES);
    int*   csr_src = (int*)alloc(sizeof(int) * N_EDGES);                   // 1.28 MB

    // xbt (tiled bf16 x) lives in d_out: 1250*32 tiles * 1KB = 40,960,000 B
    // = exactly out_size*4.  d_out is dead until aggregate_ln overwrites it.
    short* xbt = (short*)d_out;

    hipMemsetAsync(deg, 0, sizeof(int) * N_NODES, stream);

    fused_pre<<<DEG_BLOCKS + CONV_BLOCKS + PREP_BLOCKS, 256, 0, stream>>>(
        x, ei, Wsrc, Wdst, att_src, att_dst, xbt, wbtt, deg);

    gemm_scan<<<NWG + 1, 256, 0, stream>>>(
        xbt, wbtt, xsb, a_srcv, a_dstv, deg, off, cursor);

    edge_scatter<<<N_EDGES / 256, 256, 0, stream>>>(ei, cursor, csr_src);

    aggregate_ln<<<N_NODES / 4, 256, 0, stream>>>(
        off, csr_src, a_srcv, a_dstv, xsb, bias, gamma, beta, prelu_a, out);
}